// Round 1
// baseline (1468.854 us; speedup 1.0000x reference)
//
#include <hip/hip_runtime.h>
#include <hip/hip_bf16.h>
#include <stdint.h>

#define HID   1024
#define KD    2048      // reduction dim = 2*HID
#define NK    (KD/64)   // 32 K-tiles of 64
#define BATCH 32
#define SRC   2048

typedef __attribute__((ext_vector_type(4))) float  f32x4;
typedef __attribute__((ext_vector_type(8))) __bf16 bf16x8;
typedef __attribute__((ext_vector_type(4))) __bf16 bf16x4;

// ---------------------------------------------------------------- prep: cast W_e -> bf16 contiguous, zero logits(=d_out)
__global__ __launch_bounds__(256) void prep_w_kernel(const float* __restrict__ attn_w,
                                                     __bf16* __restrict__ wbuf,
                                                     float* __restrict__ out)
{
    int gid = blockIdx.x * 256 + threadIdx.x;          // 0..524287
    int p = gid << 2;                                  // element quad
    int h = p >> 11;                                   // 0..1023
    int e = p & 2047;
    f32x4 w = *(const f32x4*)(attn_w + (size_t)h * 3072 + HID + e);
    bf16x4 o = { (__bf16)w[0], (__bf16)w[1], (__bf16)w[2], (__bf16)w[3] };
    *(bf16x4*)(wbuf + p) = o;
    if (gid < 16384) {                                 // zero all 65536 logits
        f32x4 z = {0.f, 0.f, 0.f, 0.f};
        ((f32x4*)out)[gid] = z;
    }
}

// ---------------------------------------------------------------- prep: hb[b][h] = hidden@w_h.T + bias  (f32, exact)
__global__ __launch_bounds__(256) void prep_h_kernel(const float* __restrict__ hidden,
                                                     const float* __restrict__ attn_w,
                                                     const float* __restrict__ attn_b,
                                                     float* __restrict__ hb)
{
    int gid = blockIdx.x * 256 + threadIdx.x;          // 0..32767
    int b = gid & 31;
    int h = gid >> 5;
    const float* hp = hidden + b * HID;
    const float* wp = attn_w + (size_t)h * 3072;       // w_h row h
    float acc = 0.f;
    #pragma unroll 4
    for (int k = 0; k < HID; k += 4) {
        f32x4 hv = *(const f32x4*)(hp + k);
        f32x4 wv = *(const f32x4*)(wp + k);
        acc += hv[0]*wv[0] + hv[1]*wv[1] + hv[2]*wv[2] + hv[3]*wv[3];
    }
    hb[b * HID + h] = acc + attn_b[h];
}

// ---------------------------------------------------------------- fused GEMM + tanh + v-dot -> atomic logits
// A = enc (65536 x 2048 f32, contiguous rows, m = s*32+b), B = wbuf (1024 x 2048 bf16, K-major rows)
// 128x128 tile, BK=64, 4 waves (2x2), each wave 64x64 via 4x4 frags of 16x16x32 bf16 MFMA.
__global__ __launch_bounds__(256, 2)
void fused_attn_gemm(const float* __restrict__ enc,
                     const __bf16* __restrict__ wb,
                     const float* __restrict__ hb,
                     const float* __restrict__ v_w,
                     float* __restrict__ out)          // [32][2048] logits, atomically accumulated
{
    const int bid = blockIdx.x;
    const int mt  = bid >> 3;          // 512 M-tiles
    const int nc  = bid & 7;           // 8 N-chunks (== XCD id under round-robin)
    const int m0  = mt * 128;
    const int h0  = nc * 128;

    const int tid  = threadIdx.x;
    const int wid  = tid >> 6;
    const int lane = tid & 63;
    const int wr   = wid >> 1;
    const int wc   = wid & 1;
    const int l15  = lane & 15;
    const int g    = lane >> 4;

    __shared__ __attribute__((aligned(16))) __bf16 lA[2][128 * 64];
    __shared__ __attribute__((aligned(16))) __bf16 lB[2][128 * 64];

    f32x4 acc[4][4];
    #pragma unroll
    for (int i = 0; i < 4; ++i)
        #pragma unroll
        for (int j = 0; j < 4; ++j)
            acc[i][j] = (f32x4){0.f, 0.f, 0.f, 0.f};

    // ---- A staging geometry: thread -> row (tid>>1), 32 f32 at col-half (tid&1)*32
    const int ar = tid >> 1;
    const int ah = tid & 1;
    const float* aBase = enc + (size_t)(m0 + ar) * KD + ah * 32;
    const int aswz = ar & 7;

    // ---- B staging via global_load_lds (linear LDS dest, inverse-swizzled global src)
    int bofs[4];
    const __bf16* bsrc[4];
    #pragma unroll
    for (int i = 0; i < 4; ++i) {
        int o  = (i * 256 + tid) * 16;   // byte offset in 16KiB tile
        int r  = o >> 7;                 // tile row 0..127
        int pc = (o >> 4) & 7;           // physical 16B chunk
        int c  = pc ^ (r & 7);           // logical chunk (XOR involution)
        bofs[i] = o >> 1;                // in shorts/__bf16
        bsrc[i] = wb + (size_t)(h0 + r) * KD + c * 8;
    }

    // ---- fragment read offsets (row&7 == l15&7 for all frags)
    int rA[4], rB[4];
    #pragma unroll
    for (int i = 0; i < 4; ++i) {
        rA[i] = (wr * 64 + i * 16 + l15) * 64;
        rB[i] = (wc * 64 + i * 16 + l15) * 64;
    }
    const int sw0 = ((0 + g) ^ (l15 & 7)) * 8;
    const int sw1 = ((4 + g) ^ (l15 & 7)) * 8;

    f32x4 sreg[8];

    auto loadA = [&](int kt) {
        #pragma unroll
        for (int q = 0; q < 8; ++q)
            sreg[q] = *(const f32x4*)(aBase + kt * 64 + q * 4);
    };
    auto writeA = [&](int buf) {
        #pragma unroll
        for (int q = 0; q < 4; ++q) {
            f32x4 x = sreg[2*q], y = sreg[2*q+1];
            bf16x8 v = { (__bf16)x[0], (__bf16)x[1], (__bf16)x[2], (__bf16)x[3],
                         (__bf16)y[0], (__bf16)y[1], (__bf16)y[2], (__bf16)y[3] };
            int pc = (ah * 4 + q) ^ aswz;
            *(bf16x8*)&lA[buf][ar * 64 + pc * 8] = v;
        }
    };
    auto issueB = [&](int buf, int kt) {
        #pragma unroll
        for (int i = 0; i < 4; ++i) {
            __builtin_amdgcn_global_load_lds(
                (const __attribute__((address_space(1))) void*)(bsrc[i] + kt * 64),
                (__attribute__((address_space(3))) void*)&lB[buf][bofs[i]],
                16, 0, 0);
        }
    };
    auto compute = [&](int buf) {
        #pragma unroll
        for (int ks = 0; ks < 2; ++ks) {
            const int sw = ks ? sw1 : sw0;
            bf16x8 af[4], bfv[4];
            #pragma unroll
            for (int i = 0; i < 4; ++i) af[i]  = *(const bf16x8*)&lA[buf][rA[i] + sw];
            #pragma unroll
            for (int i = 0; i < 4; ++i) bfv[i] = *(const bf16x8*)&lB[buf][rB[i] + sw];
            #pragma unroll
            for (int mi = 0; mi < 4; ++mi)
                #pragma unroll
                for (int ni = 0; ni < 4; ++ni)
                    acc[mi][ni] = __builtin_amdgcn_mfma_f32_16x16x32_bf16(
                        af[mi], bfv[ni], acc[mi][ni], 0, 0, 0);
        }
    };

    // prologue: stage tile 0
    loadA(0);
    issueB(0, 0);
    writeA(0);
    __syncthreads();

    for (int kt = 0; kt < NK; ++kt) {
        const int cur = kt & 1;
        if (kt + 1 < NK) { loadA(kt + 1); issueB(cur ^ 1, kt + 1); }  // issue-early
        compute(cur);
        if (kt + 1 < NK) writeA(cur ^ 1);                             // write-late (T14)
        __syncthreads();
    }

    // ---- epilogue: energy = tanh(acc + hb[b][h]); logit += energy * v_w[h]
    float vw[4];
    #pragma unroll
    for (int ni = 0; ni < 4; ++ni)
        vw[ni] = v_w[h0 + wc * 64 + ni * 16 + l15];

    #pragma unroll
    for (int mi = 0; mi < 4; ++mi) {
        #pragma unroll
        for (int j = 0; j < 4; ++j) {
            const int m = m0 + wr * 64 + mi * 16 + g * 4 + j;  // C/D: row=(lane>>4)*4+reg
            const int b = m & 31;
            const int s = m >> 5;
            const float* hbrow = hb + b * HID + h0 + wc * 64;
            float sum = 0.f;
            #pragma unroll
            for (int ni = 0; ni < 4; ++ni) {
                float e = acc[mi][ni][j] + hbrow[ni * 16 + l15]; // C/D: col=lane&15
                sum += tanhf(e) * vw[ni];
            }
            sum += __shfl_xor(sum, 1);
            sum += __shfl_xor(sum, 2);
            sum += __shfl_xor(sum, 4);
            sum += __shfl_xor(sum, 8);
            if (l15 == 0)
                atomicAdd(&out[b * SRC + s], sum);
        }
    }
}

// ---------------------------------------------------------------- in-place row softmax over s (row b is contiguous)
__global__ __launch_bounds__(256) void softmax_kernel(float* __restrict__ out)
{
    const int b = blockIdx.x;
    const int t = threadIdx.x;
    const int wid = t >> 6, lane = t & 63;
    __shared__ float redm[4], reds[4];

    float v[8];
    float mx = -3.4e38f;
    #pragma unroll
    for (int i = 0; i < 8; ++i) {
        v[i] = out[b * SRC + i * 256 + t];
        mx = fmaxf(mx, v[i]);
    }
    #pragma unroll
    for (int o = 1; o < 64; o <<= 1) mx = fmaxf(mx, __shfl_xor(mx, o));
    if (lane == 0) redm[wid] = mx;
    __syncthreads();
    mx = fmaxf(fmaxf(redm[0], redm[1]), fmaxf(redm[2], redm[3]));

    float sum = 0.f;
    #pragma unroll
    for (int i = 0; i < 8; ++i) { v[i] = expf(v[i] - mx); sum += v[i]; }
    #pragma unroll
    for (int o = 1; o < 64; o <<= 1) sum += __shfl_xor(sum, o);
    if (lane == 0) reds[wid] = sum;
    __syncthreads();
    sum = reds[0] + reds[1] + reds[2] + reds[3];

    const float inv = 1.f / sum;
    #pragma unroll
    for (int i = 0; i < 8; ++i) out[b * SRC + i * 256 + t] = v[i] * inv;
}

extern "C" void kernel_launch(void* const* d_in, const int* in_sizes, int n_in,
                              void* d_out, int out_size, void* d_ws, size_t ws_size,
                              hipStream_t stream)
{
    const float* hidden = (const float*)d_in[0];   // [32][1024]
    const float* enc    = (const float*)d_in[1];   // [2048][32][2048] == A[65536][2048]
    const float* attn_w = (const float*)d_in[2];   // [1024][3072]
    const float* attn_b = (const float*)d_in[3];   // [1024]
    const float* v_w    = (const float*)d_in[4];   // [1024]
    float* out = (float*)d_out;                    // [32][2048]

    __bf16* wbuf = (__bf16*)d_ws;                              // 4 MiB bf16 W_e
    float*  hb   = (float*)((char*)d_ws + (size_t)(4u << 20)); // 128 KiB hb

    prep_w_kernel<<<2048, 256, 0, stream>>>(attn_w, wbuf, out);
    prep_h_kernel<<<128, 256, 0, stream>>>(hidden, attn_w, attn_b, hb);
    fused_attn_gemm<<<4096, 256, 0, stream>>>(enc, wbuf, hb, v_w, out);
    softmax_kernel<<<32, 256, 0, stream>>>(out);
}